// Round 16
// baseline (126.384 us; speedup 1.0000x reference)
//
#include <hip/hip_runtime.h>

// ---------------------------------------------------------------------------
// GalerkinAttention on MI355X (gfx950), round 16 = r15 champion (126.0us) +
// k1 Bs DOUBLE-BUFFER (B(t+1) staged during iter t -> B's L2 latency moves
// off the critical path; the per-iter vmcnt wait becomes a steady-state
// no-op). LDS 32->48KB (>=3 blocks/CU; measured residency was ~2.3 anyway).
// Everything else byte-identical to r15 (bf16 Ppart, parallel preduce/k3a).
//
// Shapes: B=4, N=8192, D=512, H=8, Dh=64. Algebra: y = x @ M_b^T + b_out,
//   M_b[d'][d] = sum_h W_out[d',h-blk] . P_bh . W_q[h-blk,d] / n
//
// k1 FIFO vmcnt ledger (per thread):
//   prologue: A(0):8 f32 loads, then B(0):4 gload_lds -> [A0:8, B0:4]
//   iter t: cvt reads A(t) -> compiler waits the A-loads (issued iter t-1,
//   ~arrived; at t=0 leaves B0 in flight). Then issue B(t+1):4, A(t+1):8.
//   Pre-barrier: s_waitcnt vmcnt(12) lgkmcnt(0) -> drains B(t) (t=0) /
//   no-op (t>=1, already drained by cvt's implicit wait), flushes ds_writes.
//   Tail t=7: vmcnt(0). Compute reads Bs[t&1]; B(t+1) lands in Bs[(t+1)&1].
//
// MFMA 16x16x32 bf16 (verified r1-15):
//   A frag: lane l holds A[row=l&15][k = ks*32 + (l>>4)*8 + e]
//   B frag: lane l holds B[col=l&15][same k]
//   C/D   : lane l reg r -> C[row=(l>>4)*4+r][col=l&15]
// LDS swizzle (8-short XOR, PMC-verified 0 conflicts):
//   stage src col pre-swizzled ((l&7)^(l>>3))*8; read col ^ ((c16&7)<<3)
// Epilogue kn/vn LDS ([64 d][128 n], 16B-granular XOR):
//   phys_short(d,n) = d*128 + ((n>>3)^(d&15))*8 + (n&7)
// ---------------------------------------------------------------------------

typedef __attribute__((ext_vector_type(8))) short bf16x8;
typedef __attribute__((ext_vector_type(4))) float f32x4;
typedef __attribute__((ext_vector_type(4))) unsigned short u16x4;
typedef __attribute__((ext_vector_type(4))) unsigned int u32x4;

__device__ __forceinline__ unsigned short f2bf(float f) {
  unsigned int u = __builtin_bit_cast(unsigned int, f);
  u += 0x7FFFu + ((u >> 16) & 1u);   // RNE
  return (unsigned short)(u >> 16);
}

__device__ __forceinline__ float bf2f(unsigned short h) {
  unsigned int u = ((unsigned int)h) << 16;
  return __builtin_bit_cast(float, u);
}

__device__ __forceinline__ unsigned int cvt2(float lo, float hi) {
  return ((unsigned int)f2bf(hi) << 16) | (unsigned int)f2bf(lo);
}

__device__ __forceinline__ f32x4 mfma16(bf16x8 a, bf16x8 b, f32x4 c) {
  return __builtin_amdgcn_mfma_f32_16x16x32_bf16(a, b, c, 0, 0, 0);
}

__device__ __forceinline__ void gload16(const void* g, void* l) {
  __builtin_amdgcn_global_load_lds(
      (const __attribute__((address_space(1))) void*)g,
      (__attribute__((address_space(3))) void*)l, 16, 0, 0);
}

// ------------------------ K0: convert weights (merged) ----------------------
__global__ void k_cvt_w(const float* __restrict__ Wqkv,
                        const float* __restrict__ Wout,
                        unsigned short* __restrict__ Wb,
                        unsigned short* __restrict__ Wob) {
  int i = blockIdx.x * 256 + threadIdx.x;
  const float4* src;
  u16x4* dst;
  if (i < 196608) { src = (const float4*)Wqkv + i; dst = (u16x4*)Wb + i; }
  else { i -= 196608; src = (const float4*)Wout + i; dst = (u16x4*)Wob + i; }
  float4 v = *src;
  u16x4 o;
  o[0] = f2bf(v.x); o[1] = f2bf(v.y); o[2] = f2bf(v.z); o[3] = f2bf(v.w);
  *dst = o;
}

// ------------ K1: kv GEMM (A reg-staged f32, Bs dbuf) + LN + P --------------
// 1D grid 2048 (XCD-swizzled): wgid=(bid&7)*256+(bid>>3); rt=wgid>>3, h=wgid&7
__launch_bounds__(256, 3)
__global__ void k1_kvp(const float* __restrict__ x,
                       const unsigned short* __restrict__ wqkvb,
                       const float* __restrict__ gK, const float* __restrict__ bK,
                       const float* __restrict__ gV, const float* __restrict__ bV,
                       unsigned short* __restrict__ Ppart) {
  __shared__ __align__(16) unsigned short As[8192];      // 16 KB: A [128][64]
  __shared__ __align__(16) unsigned short Bs[2][8192];   // 32 KB: B dbuf
  const int bid = (int)blockIdx.x;
  const int wgid = (bid & 7) * 256 + (bid >> 3);      // bijective (2048%8==0)
  const int rt = wgid >> 3, h = wgid & 7;
  const int tid = (int)threadIdx.x;
  const int l = tid & 63, w = tid >> 6;
  const int wr = w >> 1, wc = w & 1;
  const int g = l >> 4, c16 = l & 15;
  const int row0 = rt * 128;
  const int swz = ((l & 7) ^ (l >> 3)) * 8;           // logical col in 64-blk

  const float* gx = x + (size_t)(row0 + w * 32 + (l >> 3)) * 512 + swz;
  const int bcol = (w < 2) ? (512 + h * 64 + w * 32) : (1024 + h * 64 + (w - 2) * 32);
  const unsigned short* gsB = wqkvb + (bcol + (l >> 3)) * 512 + swz;
  unsigned short* la = As + w * 2048 + l * 8;         // + j*512 per row-slice

  f32x4 acc[4][4] = {};
  float4 pf[8];

  // prologue: A(0) f32 loads FIRST (oldest), then B(0) gload_lds
#pragma unroll
  for (int j = 0; j < 4; ++j) {
    pf[2 * j]     = *(const float4*)(gx + j * 4096);
    pf[2 * j + 1] = *(const float4*)(gx + j * 4096 + 4);
  }
  __builtin_amdgcn_sched_barrier(0);
#pragma unroll
  for (int j = 0; j < 4; ++j)
    gload16(gsB + j * 8 * 512, (unsigned short*)Bs[0] + w * 2048 + j * 512);
  __builtin_amdgcn_sched_barrier(0);

  for (int kt = 0; kt < 8; ++kt) {
    // convert + write A(kt); compiler's implicit wait covers loads issued
    // one iteration ago (prologue loads at kt=0: leaves B(0) in flight)
#pragma unroll
    for (int j = 0; j < 4; ++j) {
      u32x4 c;
      c[0] = cvt2(pf[2 * j].x, pf[2 * j].y);
      c[1] = cvt2(pf[2 * j].z, pf[2 * j].w);
      c[2] = cvt2(pf[2 * j + 1].x, pf[2 * j + 1].y);
      c[3] = cvt2(pf[2 * j + 1].z, pf[2 * j + 1].w);
      *(u32x4*)(la + j * 512) = c;
    }
    __builtin_amdgcn_sched_barrier(0);
    if (kt < 7) {
      // stage B(kt+1) into the ALTERNATE buffer (consumed next iteration)
      unsigned short* bdst = (unsigned short*)Bs[(kt + 1) & 1] + w * 2048;
#pragma unroll
      for (int j = 0; j < 4; ++j)
        gload16(gsB + (kt + 1) * 64 + j * 8 * 512, bdst + j * 512);
      __builtin_amdgcn_sched_barrier(0);
      // prefetch A(kt+1) f32 -- in flight across the whole next iteration
#pragma unroll
      for (int j = 0; j < 4; ++j) {
        pf[2 * j]     = *(const float4*)(gx + (kt + 1) * 64 + j * 4096);
        pf[2 * j + 1] = *(const float4*)(gx + (kt + 1) * 64 + j * 4096 + 4);
      }
      __builtin_amdgcn_sched_barrier(0);
      // drains B(kt) at kt=0; steady-state no-op (12 newest stay in flight)
      asm volatile("s_waitcnt vmcnt(12) lgkmcnt(0)" ::: "memory");
    } else {
      asm volatile("s_waitcnt vmcnt(0) lgkmcnt(0)" ::: "memory");
    }
    __builtin_amdgcn_sched_barrier(0);
    __builtin_amdgcn_s_barrier();        // tile ready
    // compute on As + Bs[kt&1]
    const unsigned short* Bb = (const unsigned short*)Bs[kt & 1];
#pragma unroll
    for (int ks = 0; ks < 2; ++ks) {
      const int kcol = (ks * 32 + g * 8) ^ ((c16 & 7) << 3);
      bf16x8 af[4], bfv[4];
#pragma unroll
      for (int mi = 0; mi < 4; ++mi)
        af[mi] = *(const bf16x8*)&As[(wr * 64 + mi * 16 + c16) * 64 + kcol];
#pragma unroll
      for (int ni = 0; ni < 4; ++ni)
        bfv[ni] = *(const bf16x8*)&Bb[(wc * 64 + ni * 16 + c16) * 64 + kcol];
#pragma unroll
      for (int mi = 0; mi < 4; ++mi)
#pragma unroll
        for (int ni = 0; ni < 4; ++ni)
          acc[mi][ni] = mfma16(af[mi], bfv[ni], acc[mi][ni]);
    }
    __builtin_amdgcn_sched_barrier(0);
    __builtin_amdgcn_s_barrier();        // As free for next kt's writes
  }

  // ---- per-head LayerNorm (wc=0 -> k, wc=1 -> v)
  const float* gamma = (wc == 0) ? gK : gV;
  const float* beta  = (wc == 0) ? bK : bV;
  float gm[4], bt[4];
#pragma unroll
  for (int ni = 0; ni < 4; ++ni) {
    gm[ni] = gamma[h * 64 + ni * 16 + c16];
    bt[ni] = beta[h * 64 + ni * 16 + c16];
  }
  // kn -> As ([64 d][128 n]), vn -> Bs[0]
  unsigned short* dst = (wc == 0) ? As : (unsigned short*)Bs[0];
#pragma unroll
  for (int mi = 0; mi < 4; ++mi) {
    float mean4[4], rs4[4];
#pragma unroll
    for (int r = 0; r < 4; ++r) {
      float a0 = acc[mi][0][r], a1 = acc[mi][1][r];
      float a2 = acc[mi][2][r], a3 = acc[mi][3][r];
      float s1 = a0 + a1 + a2 + a3;
      float s2 = a0 * a0 + a1 * a1 + a2 * a2 + a3 * a3;
#pragma unroll
      for (int m = 1; m <= 8; m <<= 1) {   // reduce over 16-lane col group
        s1 += __shfl_xor(s1, m, 64);
        s2 += __shfl_xor(s2, m, 64);
      }
      const float mean = s1 * (1.0f / 64.0f);
      const float var = s2 * (1.0f / 64.0f) - mean * mean;
      mean4[r] = mean;
      rs4[r] = rsqrtf(var + 1e-5f);
    }
    const int n0 = wr * 64 + mi * 16 + g * 4;
#pragma unroll
    for (int ni = 0; ni < 4; ++ni) {
      u16x4 o;
#pragma unroll
      for (int r = 0; r < 4; ++r)
        o[r] = f2bf((acc[mi][ni][r] - mean4[r]) * rs4[r] * gm[ni] + bt[ni]);
      // phys8 = (n>>3) ^ (d&15); d&15 == c16
      *(u16x4*)&dst[(ni * 16 + c16) * 128 + (((n0 >> 3) ^ c16) << 3) + (n0 & 7)] = o;
    }
  }
  __syncthreads();

  // ---- P-partial: wave w covers dh rows w*16..w*16+15, all 64 dv, n=128
  const unsigned short* Vl = (const unsigned short*)Bs[0];
  f32x4 pacc[4] = {};
#pragma unroll
  for (int ks = 0; ks < 4; ++ks) {
    const int grp = ((ks * 4 + g) ^ c16) << 3;
    bf16x8 af = *(const bf16x8*)&As[(w * 16 + c16) * 128 + grp];
#pragma unroll
    for (int ni = 0; ni < 4; ++ni) {
      bf16x8 bv = *(const bf16x8*)&Vl[(ni * 16 + c16) * 128 + grp];
      pacc[ni] = mfma16(af, bv, pacc[ni]);
    }
  }
  // bf16 partial stores: Ppart[bh][slab][dh][dv], slab = rt & 63
  const int bh = (rt >> 6) * 8 + h;
  unsigned short* Pp = Ppart + ((size_t)(bh * 64 + (rt & 63))) * 4096;
#pragma unroll
  for (int ni = 0; ni < 4; ++ni)
#pragma unroll
    for (int r = 0; r < 4; ++r)
      Pp[(w * 16 + g * 4 + r) * 64 + ni * 16 + c16] = f2bf(pacc[ni][r]);
}

// ---------------- KR: P[bh] = sum over 64 slabs of Ppart (bf16) -------------
__launch_bounds__(256)
__global__ void k_preduce(const unsigned short* __restrict__ Ppart,
                          float* __restrict__ P) {
  const int bh = blockIdx.x;
  const int e = blockIdx.y * 256 + threadIdx.x;
  const unsigned short* src = Ppart + (size_t)bh * 64 * 4096 + e;
  float s = 0.f;
#pragma unroll 8
  for (int sl = 0; sl < 64; ++sl) s += bf2f(src[sl * 4096]);
  P[bh * 4096 + e] = s;
}

// ------------- K3a: Gt[b][d][h*64+dv] = sum_dh P[bh][dh][dv]*Wq[h*64+dh][d]/n
__launch_bounds__(256)
__global__ void k3a_g(const float* __restrict__ Wqkv,
                      const float* __restrict__ P,
                      unsigned short* __restrict__ Gt) {
  __shared__ float Pl[64 * 64];
  const int bh = blockIdx.x, dd = blockIdx.y;
  const int b = bh >> 3, h = bh & 7;
  const int t = (int)threadIdx.x;
  for (int i = t; i < 1024; i += 256)
    ((float4*)Pl)[i] = ((const float4*)(P + bh * 4096))[i];
  __syncthreads();

  const int qg = t >> 6, dl = t & 63;
  const int d = dd * 64 + dl;
  float acc[16] = {};
  for (int dh = 0; dh < 64; ++dh) {
    const float wq = Wqkv[(h * 64 + dh) * 512 + d];
    const float* pr = &Pl[dh * 64 + qg * 16];
#pragma unroll
    for (int i = 0; i < 16; ++i) acc[i] += pr[i] * wq;
  }
  unsigned short* go = &Gt[(b * 512 + d) * 512 + h * 64 + qg * 16];
#pragma unroll
  for (int i = 0; i < 16; ++i) go[i] = f2bf(acc[i] * (1.0f / 8192.0f));
}

// ----------------------- 128^2 single-buffer GEMM pieces --------------------
__device__ __forceinline__ void stage_tile(const unsigned short* pa,
                                           const unsigned short* pb,
                                           unsigned short* As, unsigned short* Bs,
                                           int w) {
#pragma unroll
  for (int j = 0; j < 4; ++j) {
    gload16(pa + j * 8 * 512, As + w * 2048 + j * 512);
    gload16(pb + j * 8 * 512, Bs + w * 2048 + j * 512);
  }
}

__device__ __forceinline__ void compute_tile(const unsigned short* As,
                                             const unsigned short* Bs,
                                             int wr, int wc, int g, int c16,
                                             f32x4 acc[4][4]) {
#pragma unroll
  for (int ks = 0; ks < 2; ++ks) {
    const int kcol = (ks * 32 + g * 8) ^ ((c16 & 7) << 3);
    bf16x8 af[4], bfv[4];
#pragma unroll
    for (int mi = 0; mi < 4; ++mi)
      af[mi] = *(const bf16x8*)&As[(wr * 64 + mi * 16 + c16) * 64 + kcol];
#pragma unroll
    for (int ni = 0; ni < 4; ++ni)
      bfv[ni] = *(const bf16x8*)&Bs[(wc * 64 + ni * 16 + c16) * 64 + kcol];
#pragma unroll
    for (int mi = 0; mi < 4; ++mi)
#pragma unroll
      for (int ni = 0; ni < 4; ++ni)
        acc[mi][ni] = mfma16(af[mi], bfv[ni], acc[mi][ni]);
  }
}

// ----------- K3b: M_b[d'][d] = sum_e Wout[d'][e] * Gt_b[d][e] ---------------
__launch_bounds__(256)
__global__ void k3b_m(const unsigned short* __restrict__ wob,
                      const unsigned short* __restrict__ Gt,
                      unsigned short* __restrict__ Mb) {
  __shared__ __align__(16) unsigned short As[8192];
  __shared__ __align__(16) unsigned short Bs[8192];
  const int rt = blockIdx.x, ct = blockIdx.y, b = blockIdx.z;
  const int tid = (int)threadIdx.x;
  const int l = tid & 63, w = tid >> 6;
  const int wr = w >> 1, wc = w & 1;
  const int g = l >> 4, c16 = l & 15;
  const int row0 = rt * 128, col0 = ct * 128;
  const int swz = ((l & 7) ^ (l >> 3)) * 8;

  const unsigned short* gsA = wob + (row0 + w * 32 + (l >> 3)) * 512 + swz;
  const unsigned short* gsB = Gt + b * 262144 + (col0 + w * 32 + (l >> 3)) * 512 + swz;

  f32x4 acc[4][4] = {};
  for (int kt = 0; kt < 8; ++kt) {
    stage_tile(gsA + kt * 64, gsB + kt * 64, As, Bs, w);
    __syncthreads();
    compute_tile(As, Bs, wr, wc, g, c16, acc);
    __syncthreads();
  }

#pragma unroll
  for (int mi = 0; mi < 4; ++mi)
#pragma unroll
    for (int ni = 0; ni < 4; ++ni) {
      const int colg = col0 + wc * 64 + ni * 16 + c16;
#pragma unroll
      for (int r = 0; r < 4; ++r) {
        const int rowg = row0 + wr * 64 + mi * 16 + g * 4 + r;
        Mb[(b * 512 + rowg) * 512 + colg] = f2bf(acc[mi][ni][r]);
      }
    }
}

// ---------------- K4: y = x @ M_b^T + b_out (A reg-staged f32) --------------
// 1D grid 1024 (XCD-swizzled): wgid=(bid&7)*128+(bid>>3); rt=wgid>>2, ct=wgid&3
__launch_bounds__(256, 3)
__global__ void k4_final(const float* __restrict__ x,
                         const unsigned short* __restrict__ Mb,
                         const float* __restrict__ bout,
                         float* __restrict__ y) {
  __shared__ __align__(16) unsigned short As[8192];
  __shared__ __align__(16) unsigned short Bs[8192];
  const int bid = (int)blockIdx.x;
  const int wgid = (bid & 7) * 128 + (bid >> 3);      // bijective (1024%8==0)
  const int rt = wgid >> 2, ct = wgid & 3;
  const int tid = (int)threadIdx.x;
  const int l = tid & 63, w = tid >> 6;
  const int wr = w >> 1, wc = w & 1;
  const int g = l >> 4, c16 = l & 15;
  const int row0 = rt * 128, col0 = ct * 128;
  const int bb = row0 >> 13;
  const int swz = ((l & 7) ^ (l >> 3)) * 8;

  const float* gx = x + (size_t)(row0 + w * 32 + (l >> 3)) * 512 + swz;
  const unsigned short* gsB =
      Mb + (size_t)bb * 262144 + (col0 + w * 32 + (l >> 3)) * 512 + swz;
  unsigned short* la = As + w * 2048 + l * 8;

  f32x4 acc[4][4] = {};
  float4 pf[8];
#pragma unroll
  for (int j = 0; j < 4; ++j) {
    pf[2 * j]     = *(const float4*)(gx + j * 4096);
    pf[2 * j + 1] = *(const float4*)(gx + j * 4096 + 4);
  }

  for (int kt = 0; kt < 8; ++kt) {
#pragma unroll
    for (int j = 0; j < 4; ++j) {
      u32x4 c;
      c[0] = cvt2(pf[2 * j].x, pf[2 * j].y);
      c[1] = cvt2(pf[2 * j].z, pf[2 * j].w);
      c[2] = cvt2(pf[2 * j + 1].x, pf[2 * j + 1].y);
      c[3] = cvt2(pf[2 * j + 1].z, pf[2 * j + 1].w);
      *(u32x4*)(la + j * 512) = c;
    }
#pragma unroll
    for (int j = 0; j < 4; ++j)
      gload16(gsB + kt * 64 + j * 8 * 512, Bs + w * 2048 + j * 512);
    __builtin_amdgcn_sched_barrier(0);
    if (kt < 7) {
#pragma unroll
      for (int j = 0; j < 4; ++j) {
        pf[2 * j]     = *(const float4*)(gx + (kt + 1) * 64 + j * 4096);
        pf[2 * j + 1] = *(const float4*)(gx + (kt + 1) * 64 + j * 4096 + 4);
      }
      asm volatile("s_waitcnt vmcnt(8) lgkmcnt(0)" ::: "memory");
    } else {
      asm volatile("s_waitcnt vmcnt(0) lgkmcnt(0)" ::: "memory");
    }
    __builtin_amdgcn_sched_barrier(0);
    __builtin_amdgcn_s_barrier();
#pragma unroll
    for (int ks = 0; ks < 2; ++ks) {
      const int kcol = (ks * 32 + g * 8) ^ ((c16 & 7) << 3);
      bf16x8 af[4], bfv[4];
#pragma unroll
      for (int mi = 0; mi < 4; ++mi)
        af[mi] = *(const bf16x8*)&As[(wr * 64 + mi * 16 + c16) * 64 + kcol];
#pragma unroll
      for (int ni = 0; ni < 4; ++ni)
        bfv[ni] = *(const bf16x8*)&Bs[(wc * 64 + ni * 16 + c16) * 64 + kcol];
#pragma unroll
      for (int mi = 0; mi < 4; ++mi)
#pragma unroll
        for (int ni = 0; ni < 4; ++ni)
          acc[mi][ni] = mfma16(af[mi], bfv[ni], acc[mi][ni]);
    }
    __builtin_amdgcn_sched_barrier(0);
    __builtin_amdgcn_s_barrier();
  }

  float bo[4];
#pragma unroll
  for (int ni = 0; ni < 4; ++ni)
    bo[ni] = bout[col0 + wc * 64 + ni * 16 + c16];
#pragma unroll
  for (int mi = 0; mi < 4; ++mi)
#pragma unroll
    for (int ni = 0; ni < 4; ++ni) {
      const int colg = col0 + wc * 64 + ni * 16 + c16;
#pragma unroll
      for (int r = 0; r < 4; ++r) {
        const int rowg = row0 + wr * 64 + mi * 16 + g * 4 + r;
        y[rowg * 512 + colg] = acc[mi][ni][r] + bo[ni];
      }
    }
}

// ---------------------------------------------------------------------------
extern "C" void kernel_launch(void* const* d_in, const int* in_sizes, int n_in,
                              void* d_out, int out_size, void* d_ws, size_t ws_size,
                              hipStream_t stream) {
  (void)in_sizes; (void)n_in; (void)out_size; (void)ws_size;
  const float* x    = (const float*)d_in[0];
  const float* Wqkv = (const float*)d_in[1];
  const float* gK   = (const float*)d_in[2];
  const float* bK   = (const float*)d_in[3];
  const float* gV   = (const float*)d_in[4];
  const float* bV   = (const float*)d_in[5];
  const float* Wout = (const float*)d_in[6];
  const float* bout = (const float*)d_in[7];
  float* y = (float*)d_out;

  // workspace carve (~23 MB)
  char* w = (char*)d_ws;
  unsigned short* Wb    = (unsigned short*)(w);             //  1,572,864
  unsigned short* Wob   = (unsigned short*)(w + 1572864);   //    524,288
  float*          P     = (float*)         (w + 2097152);   //    524,288
  unsigned short* Gt    = (unsigned short*)(w + 2621440);   //  2,097,152
  unsigned short* Mb    = (unsigned short*)(w + 4718592);   //  2,097,152
  unsigned short* Ppart = (unsigned short*)(w + 6815744);   // 16,777,216

  k_cvt_w<<<1024, 256, 0, stream>>>(Wqkv, Wout, Wb, Wob);

  k1_kvp<<<2048, 256, 0, stream>>>(x, Wb, gK, bK, gV, bV, Ppart);
  k_preduce<<<dim3(32, 16), 256, 0, stream>>>(Ppart, P);
  k3a_g<<<dim3(32, 8), 256, 0, stream>>>(Wqkv, P, Gt);
  k3b_m<<<dim3(4, 4, 4), 256, 0, stream>>>(Wob, Gt, Mb);
  k4_final<<<1024, 256, 0, stream>>>(x, Mb, bout, y);
}